// Round 1
// baseline (2050.563 us; speedup 1.0000x reference)
//
#include <hip/hip_runtime.h>
#include <stdint.h>

#define DD 256
#define DINF 128

typedef __attribute__((ext_vector_type(8))) short short8;
typedef __attribute__((ext_vector_type(4))) float f32x4;

__device__ __forceinline__ short f2bf(float f) {
    union { float f; uint32_t u; } c{f};
    uint32_t r = (c.u + 0x7fffu + ((c.u >> 16) & 1u)) >> 16;
    return (short)(uint16_t)r;
}

__device__ __forceinline__ float bf2f(uint16_t b) {
    union { uint32_t u; float f; } c;
    c.u = ((uint32_t)b) << 16;
    return c.f;
}

// ---------------- CSR build ----------------
__global__ void k_hist(const int* __restrict__ rows, int* __restrict__ counts, int E) {
    int e = blockIdx.x * blockDim.x + threadIdx.x;
    if (e < E) atomicAdd(&counts[rows[e] + 1], 1);
}

__global__ void k_scan1(const int* __restrict__ counts, int* __restrict__ part,
                        int* __restrict__ blksum, int n1) {
    __shared__ int tmp[1024];
    int b = blockIdx.x, t = threadIdx.x, i = b * 1024 + t;
    int v = (i < n1) ? counts[i] : 0;
    tmp[t] = v;
    __syncthreads();
    for (int off = 1; off < 1024; off <<= 1) {
        int a = (t >= off) ? tmp[t - off] : 0;
        __syncthreads();
        tmp[t] += a;
        __syncthreads();
    }
    if (i < n1) part[i] = tmp[t];
    if (t == 1023) blksum[b] = tmp[t];
}

__global__ void k_scan2(int* __restrict__ blksum, int nb) {
    __shared__ int tmp[1024];
    int t = threadIdx.x;
    int v = (t < nb) ? blksum[t] : 0;
    tmp[t] = v;
    __syncthreads();
    for (int off = 1; off < 1024; off <<= 1) {
        int a = (t >= off) ? tmp[t - off] : 0;
        __syncthreads();
        tmp[t] += a;
        __syncthreads();
    }
    if (t < nb) blksum[t] = tmp[t];
}

__global__ void k_scan3(const int* __restrict__ blksum, int* __restrict__ row_ptr,
                        int* __restrict__ cursor, int n1) {
    int i = blockIdx.x * blockDim.x + threadIdx.x;
    if (i < n1) {
        int b = i >> 10;
        int off = (b > 0) ? blksum[b - 1] : 0;
        int v = row_ptr[i] + off;
        row_ptr[i] = v;
        cursor[i] = v;
    }
}

__global__ void k_scatter(const int* __restrict__ rows, const int* __restrict__ cols,
                          const float* __restrict__ vals, int* __restrict__ cursor,
                          int* __restrict__ cols_s, float* __restrict__ vals_s, int E) {
    int e = blockIdx.x * blockDim.x + threadIdx.x;
    if (e < E) {
        int r = rows[e];
        int pos = atomicAdd(&cursor[r], 1);
        cols_s[pos] = cols[e];
        vals_s[pos] = vals[e];
    }
}

// ---------------- M = (W*clip(d))@W^T - I, packed in MFMA B-fragment order ----------------
__global__ void k_build_m(const float* __restrict__ W, const float* __restrict__ dvec,
                          uint16_t* __restrict__ Mpk) {
    __shared__ float u[DD];
    int n = blockIdx.x, k = threadIdx.x;
    float dj = dvec[k];
    dj = fminf(fmaxf(dj, 0.f), 1.f);
    u[k] = W[n * DD + k] * dj;
    __syncthreads();
    float acc = 0.f;
    for (int j = 0; j < DD; j++) acc += u[j] * W[k * DD + j];
    acc -= (n == k) ? 1.f : 0.f;
    int tile = n >> 4, m = n & 15, kt = k >> 5, quad = (k >> 3) & 3, j = k & 7;
    int lane = quad * 16 + m;
    Mpk[(((tile * 8 + kt) * 64 + lane) << 3) + j] = (uint16_t)f2bf(acc);
}

// ---------------- init: znb = bf16([x,0]), alpha = alpha0 ----------------
__global__ void k_init(const float* __restrict__ x, const float* __restrict__ alpha0,
                       uint16_t* __restrict__ znb, float* __restrict__ alpha, int N) {
    int idx = blockIdx.x * blockDim.x + threadIdx.x;
    int total = N * 64;
    if (idx < total) {
        int row = idx >> 6, c4 = idx & 63;
        float4 v = make_float4(0.f, 0.f, 0.f, 0.f);
        if (c4 < 32) v = ((const float4*)x)[(size_t)row * 32 + c4];
        ushort4 b;
        b.x = (uint16_t)f2bf(v.x); b.y = (uint16_t)f2bf(v.y);
        b.z = (uint16_t)f2bf(v.z); b.w = (uint16_t)f2bf(v.w);
        ((ushort4*)znb)[idx] = b;
    }
    if (idx < N) alpha[idx] = alpha0[idx];
}

// ---------------- fused: alpha update + SpMM gather + z@M (MFMA) + RK4 combine ----------
// f = alph*(az - z) + z@M + x0   (z = zsrc rows, staged in LDS; az gathered in regs)
// mode 0: zout = bf16(z + c1*f)   ; S = z + c2*f
// mode 1: zout = bf16(znb + c1*f) ; S += c2*f
// mode 2: zout = bf16(S + c2*f)
// mode 3: out(f32, first 128 cols) = S + c2*f        (final eval; zout untouched)
__global__ __launch_bounds__(256, 4) void k_fused(
    const uint16_t* __restrict__ zsrc, const uint16_t* __restrict__ znb,
    uint16_t* __restrict__ zout, float* __restrict__ S, float* __restrict__ out,
    const uint16_t* __restrict__ Mpk, const float* __restrict__ x,
    const int* __restrict__ row_ptr, const int* __restrict__ cols_s,
    const float* __restrict__ vals_s,
    const float* __restrict__ W_ih, const float* __restrict__ W_hh,
    const float* __restrict__ b_ih, const float* __restrict__ b_hh,
    const float* __restrict__ hbuf, float* __restrict__ alpha,
    int N, int mode, float c1, float c2)
{
    __shared__ uint16_t zs[32][264];   // eval-point rows, bf16   16.9 KB
    __shared__ uint16_t gs[32][264];   // z@M result, bf16        16.9 KB
    __shared__ float alph_s[32];
    // ~34 KB -> 4 blocks/CU

    int t = threadIdx.x;
    int r0 = blockIdx.x * 32;
    int wv = t >> 6;
    int lane = t & 63;

    // preload W_ih fragments for the alpha dots (L2-resident)
    float4 wih0 = ((const float4*)W_ih)[lane];
    float4 wih1 = ((const float4*)W_ih)[64 + lane];

    // P0: stage own 32 bf16 rows
    #pragma unroll
    for (int i = 0; i < 8; i++) {
        int idx = t + i * 256;
        int row = idx >> 6, c4 = idx & 63;
        int grow = r0 + row;
        ushort4 v = make_ushort4(0, 0, 0, 0);
        if (grow < N) v = ((const ushort4*)zsrc)[(size_t)grow * 64 + c4];
        *(ushort4*)&zs[row][c4 * 4] = v;
    }
    __syncthreads();

    // P1: alpha RNN update for this wave's 8 rows (rows 8*wv .. 8*wv+7)
    #pragma unroll
    for (int rr = 0; rr < 8; rr++) {
        int row = wv * 8 + rr;
        int grow = r0 + row;
        ushort4 z4 = *(const ushort4*)&zs[row][lane * 4];
        float z0 = bf2f(z4.x), z1 = bf2f(z4.y), z2 = bf2f(z4.z), z3 = bf2f(z4.w);
        float s0 = z0 * wih0.x + z1 * wih0.y + z2 * wih0.z + z3 * wih0.w;
        float s1 = z0 * wih1.x + z1 * wih1.y + z2 * wih1.z + z3 * wih1.w;
        #pragma unroll
        for (int off = 32; off >= 1; off >>= 1) {
            s0 += __shfl_down(s0, off, 64);
            s1 += __shfl_down(s1, off, 64);
        }
        if (lane == 0 && grow < N) {
            float h0 = hbuf[grow * 2], h1 = hbuf[grow * 2 + 1];
            float cc0 = b_ih[0] + b_hh[0] + h0 * W_hh[0] + h1 * W_hh[1];
            float cc1 = b_ih[1] + b_hh[1] + h0 * W_hh[2] + h1 * W_hh[3];
            float anew = alpha[grow] * tanhf(s0 + cc0) + tanhf(s1 + cc1);
            alpha[grow] = anew;
            alph_s[row] = 0.5f / (1.f + expf(-anew));
        }
    }

    // P2: A fragments from LDS, MFMA over 8 column tiles (Mpk B-frags from L2)
    int m = lane & 15, quad = lane >> 4;
    int arow = (wv & 1) * 16 + m;
    int whichW = wv >> 1;
    short8 afr[8];
    #pragma unroll
    for (int kt = 0; kt < 8; kt++)
        afr[kt] = *(const short8*)&zs[arow][kt * 32 + quad * 8];

    int lrb = (wv & 1) * 16 + quad * 4;
    #pragma unroll
    for (int nt = 0; nt < 8; nt++) {
        int tile = whichW * 8 + nt;
        f32x4 acc = {0.f, 0.f, 0.f, 0.f};
        #pragma unroll
        for (int kt = 0; kt < 8; kt++) {
            short8 b = ((const short8*)Mpk)[(tile * 8 + kt) * 64 + lane];
            acc = __builtin_amdgcn_mfma_f32_16x16x32_bf16(afr[kt], b, acc, 0, 0, 0);
        }
        int gcol = tile * 16 + m;
        #pragma unroll
        for (int r = 0; r < 4; r++)
            gs[lrb + r][gcol] = (uint16_t)f2bf(acc[r]);
    }
    __syncthreads();

    // P3: per-row gather (az in regs, f32) + combine + RK4; wave wv owns rows 8*wv..+7
    for (int rr = 0; rr < 8; rr++) {
        int row = wv * 8 + rr;
        int grow = r0 + row;
        if (grow >= N) continue;              // wave-uniform

        // gather az row: 4-wide unrolled for memory-level parallelism
        int es = row_ptr[grow], ee = row_ptr[grow + 1];
        float ax = 0.f, ay = 0.f, azv = 0.f, aw = 0.f;
        int i = es;
        for (; i + 3 < ee; i += 4) {
            int cA = cols_s[i], cB = cols_s[i + 1], cC = cols_s[i + 2], cD = cols_s[i + 3];
            float vA = vals_s[i], vB = vals_s[i + 1], vC = vals_s[i + 2], vD = vals_s[i + 3];
            ushort4 rA = ((const ushort4*)zsrc)[(size_t)cA * 64 + lane];
            ushort4 rB = ((const ushort4*)zsrc)[(size_t)cB * 64 + lane];
            ushort4 rC = ((const ushort4*)zsrc)[(size_t)cC * 64 + lane];
            ushort4 rD = ((const ushort4*)zsrc)[(size_t)cD * 64 + lane];
            ax  += vA * bf2f(rA.x) + vB * bf2f(rB.x) + vC * bf2f(rC.x) + vD * bf2f(rD.x);
            ay  += vA * bf2f(rA.y) + vB * bf2f(rB.y) + vC * bf2f(rC.y) + vD * bf2f(rD.y);
            azv += vA * bf2f(rA.z) + vB * bf2f(rB.z) + vC * bf2f(rC.z) + vD * bf2f(rD.z);
            aw  += vA * bf2f(rA.w) + vB * bf2f(rB.w) + vC * bf2f(rC.w) + vD * bf2f(rD.w);
        }
        for (; i < ee; i++) {
            int cA = cols_s[i];
            float vA = vals_s[i];
            ushort4 rA = ((const ushort4*)zsrc)[(size_t)cA * 64 + lane];
            ax  += vA * bf2f(rA.x);
            ay  += vA * bf2f(rA.y);
            azv += vA * bf2f(rA.z);
            aw  += vA * bf2f(rA.w);
        }

        // combine
        float al = alph_s[row];
        ushort4 z4 = *(const ushort4*)&zs[row][lane * 4];
        ushort4 g4 = *(const ushort4*)&gs[row][lane * 4];
        float zv0 = bf2f(z4.x), zv1 = bf2f(z4.y), zv2 = bf2f(z4.z), zv3 = bf2f(z4.w);
        float4 x4 = make_float4(0.f, 0.f, 0.f, 0.f);
        if (lane < 32) x4 = ((const float4*)x)[(size_t)grow * 32 + lane];
        float f0 = al * (ax  - zv0) + bf2f(g4.x) + x4.x;
        float f1 = al * (ay  - zv1) + bf2f(g4.y) + x4.y;
        float f2 = al * (azv - zv2) + bf2f(g4.z) + x4.z;
        float f3 = al * (aw  - zv3) + bf2f(g4.w) + x4.w;
        size_t b4 = (size_t)grow * 64 + lane;
        if (mode == 0) {
            ushort4 o;
            o.x = (uint16_t)f2bf(zv0 + c1 * f0); o.y = (uint16_t)f2bf(zv1 + c1 * f1);
            o.z = (uint16_t)f2bf(zv2 + c1 * f2); o.w = (uint16_t)f2bf(zv3 + c1 * f3);
            ((ushort4*)zout)[b4] = o;
            float4 s4;
            s4.x = zv0 + c2 * f0; s4.y = zv1 + c2 * f1;
            s4.z = zv2 + c2 * f2; s4.w = zv3 + c2 * f3;
            ((float4*)S)[b4] = s4;
        } else if (mode == 1) {
            ushort4 zb = ((const ushort4*)znb)[b4];
            ushort4 o;
            o.x = (uint16_t)f2bf(bf2f(zb.x) + c1 * f0);
            o.y = (uint16_t)f2bf(bf2f(zb.y) + c1 * f1);
            o.z = (uint16_t)f2bf(bf2f(zb.z) + c1 * f2);
            o.w = (uint16_t)f2bf(bf2f(zb.w) + c1 * f3);
            ((ushort4*)zout)[b4] = o;
            float4 s4 = ((const float4*)S)[b4];
            s4.x += c2 * f0; s4.y += c2 * f1; s4.z += c2 * f2; s4.w += c2 * f3;
            ((float4*)S)[b4] = s4;
        } else if (mode == 2) {
            float4 s4 = ((const float4*)S)[b4];
            ushort4 o;
            o.x = (uint16_t)f2bf(s4.x + c2 * f0); o.y = (uint16_t)f2bf(s4.y + c2 * f1);
            o.z = (uint16_t)f2bf(s4.z + c2 * f2); o.w = (uint16_t)f2bf(s4.w + c2 * f3);
            ((ushort4*)zout)[b4] = o;
        } else {
            // mode 3: final — emit f32 output (first 128 cols) directly
            if (lane < 32) {
                float4 s4 = ((const float4*)S)[b4];
                float4 o;
                o.x = s4.x + c2 * f0; o.y = s4.y + c2 * f1;
                o.z = s4.z + c2 * f2; o.w = s4.w + c2 * f3;
                ((float4*)out)[(size_t)grow * 32 + lane] = o;
            }
        }
    }
}

__global__ void k_fill(float* __restrict__ out, int n, float v) {
    int idx = blockIdx.x * blockDim.x + threadIdx.x;
    if (idx < n) out[idx] = v;
}

static inline size_t alignup(size_t v) { return (v + 255) & ~(size_t)255; }

extern "C" void kernel_launch(void* const* d_in, const int* in_sizes, int n_in,
                              void* d_out, int out_size, void* d_ws, size_t ws_size,
                              hipStream_t stream) {
    const float* x      = (const float*)d_in[0];
    const int*   erow   = (const int*)d_in[1];
    const int*   ecol   = (const int*)d_in[2];
    const float* evals  = (const float*)d_in[3];
    const float* W_ih   = (const float*)d_in[4];
    const float* W_hh   = (const float*)d_in[5];
    const float* b_ih   = (const float*)d_in[6];
    const float* b_hh   = (const float*)d_in[7];
    const float* h      = (const float*)d_in[8];
    const float* alpha0 = (const float*)d_in[9];
    const float* W      = (const float*)d_in[10];
    const float* dvec   = (const float*)d_in[11];

    int N = in_sizes[0] / DINF;
    int E = in_sizes[1];

    char* w = (char*)d_ws;
    uint16_t* znb = (uint16_t*)w; w += alignup((size_t)N * DD * 2);   //  51.2 MB
    float* S  = (float*)w;        w += alignup((size_t)N * DD * 4);   // 102.4 MB
    uint16_t* zpA = (uint16_t*)w; w += alignup((size_t)N * DD * 2);   //  51.2 MB
    float* alpha = (float*)w;     w += alignup((size_t)N * 4);
    uint16_t* Mpk = (uint16_t*)w; w += alignup((size_t)DD * DD * 2);
    int* counts = (int*)w;        w += alignup((size_t)(N + 1) * 4);  // reused as cursor
    int* row_ptr = (int*)w;       w += alignup((size_t)(N + 1) * 4);
    int* blksum = (int*)w;        w += alignup((size_t)1024 * 4);
    int* cols_s = (int*)w;        w += alignup((size_t)E * 4);
    float* vals_s = (float*)w;    w += alignup((size_t)E * 4);
    size_t need = (size_t)(w - (char*)d_ws);   // ~213 MB

    // zpB (bf16 ping-pong partner, 51.2 MB) lives in d_out; dead before the final
    // mode-3 eval overwrites d_out with the fp32 result.
    uint16_t* zpB = (uint16_t*)d_out;

    if (ws_size < need) {
        k_fill<<<(out_size + 255) / 256, 256, 0, stream>>>((float*)d_out, out_size, 1000.0f);
        return;
    }

    int n1 = N + 1, nb = (n1 + 1023) / 1024;
    hipMemsetAsync(counts, 0, (size_t)n1 * 4, stream);
    k_hist<<<(E + 255) / 256, 256, 0, stream>>>(erow, counts, E);
    k_scan1<<<nb, 1024, 0, stream>>>(counts, row_ptr, blksum, n1);
    k_scan2<<<1, 1024, 0, stream>>>(blksum, nb);
    k_scan3<<<(n1 + 255) / 256, 256, 0, stream>>>(blksum, row_ptr, counts, n1);
    k_scatter<<<(E + 255) / 256, 256, 0, stream>>>(erow, ecol, evals, counts, cols_s, vals_s, E);

    k_build_m<<<DD, DD, 0, stream>>>(W, dvec, Mpk);
    k_init<<<(N * 64 + 255) / 256, 256, 0, stream>>>(x, alpha0, znb, alpha, N);

    const float dt = 0.45f;  // T_END / N_STEPS
    int ge = (N + 31) / 32;
    for (int s = 0; s < 2; s++) {
        // eval1: z = znb -> eval point zpA
        k_fused<<<ge, 256, 0, stream>>>(znb, znb, zpA, S, nullptr, Mpk, x,
                                        row_ptr, cols_s, vals_s, W_ih, W_hh, b_ih, b_hh,
                                        h, alpha, N, 0, 0.5f * dt, dt / 6.f);
        // eval2: z = zpA -> zpB
        k_fused<<<ge, 256, 0, stream>>>(zpA, znb, zpB, S, nullptr, Mpk, x,
                                        row_ptr, cols_s, vals_s, W_ih, W_hh, b_ih, b_hh,
                                        h, alpha, N, 1, 0.5f * dt, dt / 3.f);
        // eval3: z = zpB -> zpA
        k_fused<<<ge, 256, 0, stream>>>(zpB, znb, zpA, S, nullptr, Mpk, x,
                                        row_ptr, cols_s, vals_s, W_ih, W_hh, b_ih, b_hh,
                                        h, alpha, N, 1, dt, dt / 3.f);
        if (s == 0) {
            // eval4: z = zpA -> new state znb
            k_fused<<<ge, 256, 0, stream>>>(zpA, znb, znb, S, nullptr, Mpk, x,
                                            row_ptr, cols_s, vals_s, W_ih, W_hh, b_ih, b_hh,
                                            h, alpha, N, 2, 0.f, dt / 6.f);
        } else {
            // final eval4: emit fp32 output directly (first 128 cols)
            k_fused<<<ge, 256, 0, stream>>>(zpA, znb, znb, S, (float*)d_out, Mpk, x,
                                            row_ptr, cols_s, vals_s, W_ih, W_hh, b_ih, b_hh,
                                            h, alpha, N, 3, 0.f, dt / 6.f);
        }
    }
}